// Round 5
// baseline (366.707 us; speedup 1.0000x reference)
//
#include <hip/hip_runtime.h>
#include <hip/hip_bf16.h>
#include <stdint.h>
#include <stddef.h>

typedef __attribute__((ext_vector_type(8))) short short8;
typedef __attribute__((ext_vector_type(4))) float floatx4;

#define AS_GLOBAL(p) (const __attribute__((address_space(1))) void*)(p)
#define AS_LDS(p)    (__attribute__((address_space(3))) void*)(p)

// Counted vmcnt waits (T4): keep newer tiles' loads in flight across barriers.
#define WAIT_VM(n)  asm volatile("s_waitcnt vmcnt(" #n ")" ::: "memory")
#define WAIT_LGKM0() asm volatile("s_waitcnt lgkmcnt(0)" ::: "memory")
#define SCHED_FENCE() __builtin_amdgcn_sched_barrier(0)

static constexpr int IN_DIM  = 4096;
static constexpr int OUT_DIM = 4096;
static constexpr int S_DIM   = 256;
static constexpr int S2      = 512;   // both branches concatenated along rank

// ---------------- prep: W1, W2 only (x->bf16 fused into gemm1's pipeline) ---
// blocks [0, 2048):    W1[s,i] = v2[i] * sign(V[s,i])           (4 elem/thread)
// blocks [2048, 4096): W2[o,s] = u1[o]*v1[s]*u2[s]*sign(U[o,s]) (4 elem/thread)
// ~21 MB traffic -> ~4 us (was 222 MB with the 192 MB x->bf16 pass).
__global__ void prep_kernel(const float* __restrict__ V, const float* __restrict__ v2,
                            const float* __restrict__ V_R, const float* __restrict__ v2_R,
                            const float* __restrict__ U, const float* __restrict__ u1,
                            const float* __restrict__ v1, const float* __restrict__ u2,
                            const float* __restrict__ U_R, const float* __restrict__ u1_R,
                            const float* __restrict__ v1_R, const float* __restrict__ u2_R,
                            __hip_bfloat16* __restrict__ W1,
                            __hip_bfloat16* __restrict__ W2) {
  const int bid = blockIdx.x;
  if (bid < 2048) {
    const int idx4 = (bid * 256 + threadIdx.x) * 4;   // over S2*IN_DIM
    const int i = idx4 & (IN_DIM - 1);
    const int s = idx4 >> 12;
    floatx4 w, sc;
    if (s < S_DIM) {
      w  = *(const floatx4*)(V + s * IN_DIM + i);
      sc = *(const floatx4*)(v2 + i);
    } else {
      w  = *(const floatx4*)(V_R + (s - S_DIM) * IN_DIM + i);
      sc = *(const floatx4*)(v2_R + i);
    }
    union { ushort4 v; __hip_bfloat16 h[4]; } u;
#pragma unroll
    for (int j = 0; j < 4; ++j) {
      const float sg = (w[j] > 0.f) ? 1.f : ((w[j] < 0.f) ? -1.f : 0.f);
      u.h[j] = __float2bfloat16(sg * sc[j]);
    }
    *(ushort4*)((unsigned short*)W1 + idx4) = u.v;
  } else {
    const int idx4 = ((bid - 2048) * 256 + threadIdx.x) * 4;   // over OUT_DIM*S2
    const int s = idx4 & (S2 - 1);
    const int o = idx4 >> 9;
    floatx4 w, scs;
    float sco;
    if (s < S_DIM) {
      w   = *(const floatx4*)(U + o * S_DIM + s);
      sco = u1[o];
      const floatx4 a = *(const floatx4*)(v1 + s);
      const floatx4 b = *(const floatx4*)(u2 + s);
      scs = a * b;
    } else {
      const int ss = s - S_DIM;
      w   = *(const floatx4*)(U_R + o * S_DIM + ss);
      sco = u1_R[o];
      const floatx4 a = *(const floatx4*)(v1_R + ss);
      const floatx4 b = *(const floatx4*)(u2_R + ss);
      scs = a * b;
    }
    union { ushort4 v; __hip_bfloat16 h[4]; } u;
#pragma unroll
    for (int j = 0; j < 4; ++j) {
      const float sg = (w[j] > 0.f) ? 1.f : ((w[j] < 0.f) ? -1.f : 0.f);
      u.h[j] = __float2bfloat16(sg * sco * scs[j]);
    }
    *(ushort4*)((unsigned short*)W2 + idx4) = u.v;
  }
}

// ---------------- GEMM1: H[M,512] = fp32 X[M,4096] @ W1[512,4096]^T --------
// r4's counted-vmcnt pipeline (BM=128, BN=64, BK=64, 256thr, 64x32 wave
// tiles, dbuf), with A read DIRECTLY from fp32 x, reg-staged TWO tiles deep:
//   tail(ti):       issue A(ti+2) 8x global_load_dwordx4 -> VGPR,
//                   issue B(ti+2) 2x global_load_lds            [queue: A8,B2]
//   top(ti):        vmcnt(10) -> B(ti) landed; barrier W; MFMA on tile ti
//   post-MFMA(ti):  vmcnt(2)  -> A(ti+1) regs landed (B(ti+1) stays in
//                   flight); cvt+ds_write A(ti+1) into As[(ti+1)&1];
//                   lgkmcnt(0); barrier R
// Race-safety: As[(ti+1)&1]'s previous readers all passed R(ti-1) before any
// wave reaches post-MFMA(ti) (barrier W(ti) enforces); lgkmcnt(0)+R makes
// the writes collective before iter ti+1's readers. A-loads get a full
// iteration (~1.5 phases) to land — fixes r3's one-phase-ahead failure
// (124 us, MfmaUtil 11%). The 32 cvt/thread/iter sits in r3's 91%-idle VALU.
__global__ __launch_bounds__(256, 2)
void gemm1_kernel(const float* __restrict__ X,
                  const __hip_bfloat16* __restrict__ B,
                  __hip_bfloat16* __restrict__ C) {
  constexpr int K = IN_DIM;   // 4096
  constexpr int N = S2;       // 512
  constexpr int BM = 128, BN = 64, BK = 64;
  constexpr int NT = K / BK;  // 64 tiles

  __shared__ __hip_bfloat16 As[2][BM * BK];   // 2 x 16 KB
  __shared__ __hip_bfloat16 Bs[2][BN * BK];   // 2 x 8 KB

  const int t = threadIdx.x;
  const int wave = t >> 6;
  const int lane = t & 63;
  const int r16 = lane & 15;
  const int quad = lane >> 4;

  // XCD swizzle: 512 blocks; XCD c handles M-tiles [c*8, c*8+8) x all 8 N-tiles.
  const int f = blockIdx.x;
  const int c = f & 7;
  const int l = f >> 3;              // [0,64)
  const int tm0 = (c * 8 + (l >> 3)) * BM;
  const int tn0 = (l & 7) * BN;

  const int wm = (wave & 1) * 64;
  const int wn = (wave >> 1) * 32;

  floatx4 acc[4][2] = {};

  // A reg stage: 4 chunks/thread (p = t + i*256), chunk p -> As + p*16,
  // row = p>>3, ql = (p&7)^(row&7)  (XOR-chunk swizzle preserved).
  floatx4 areg[4][2];

  auto loadA = [&](int k0) {          // 8 vmem ops (order: the A-group)
#pragma unroll
    for (int i = 0; i < 4; ++i) {
      const int p = t + i * 256;
      const int row = p >> 3;
      const int ql = (p & 7) ^ (row & 7);
      const float* gp = X + (size_t)(tm0 + row) * K + k0 + ql * 8;
      areg[i][0] = *(const floatx4*)gp;
      areg[i][1] = *(const floatx4*)(gp + 4);
    }
  };
  auto writeA = [&](int buf) {        // cvt fp32->bf16, pack, ds_write_b128
#pragma unroll
    for (int i = 0; i < 4; ++i) {
      const int p = t + i * 256;
      union { short8 v; __hip_bfloat16 h[8]; } u;
#pragma unroll
      for (int j = 0; j < 4; ++j) u.h[j]     = __float2bfloat16(areg[i][0][j]);
#pragma unroll
      for (int j = 0; j < 4; ++j) u.h[4 + j] = __float2bfloat16(areg[i][1][j]);
      *reinterpret_cast<short8*>((char*)&As[buf][0] + p * 16) = u.v;
    }
  };
  auto stageB = [&](int buf, int k0) {  // 2 vmem ops (after the A-group)
#pragma unroll
    for (int i = 0; i < 2; ++i) {
      const int p = t + i * 256;
      const int row = p >> 3;
      const int ql = (p & 7) ^ (row & 7);
      const __hip_bfloat16* gp = B + (size_t)(tn0 + row) * K + k0 + ql * 8;
      __builtin_amdgcn_global_load_lds(AS_GLOBAL(gp), AS_LDS((char*)&Bs[buf][0] + p * 16), 16, 0, 0);
    }
  };

  // prologue: tile 0 into LDS, tile 1 in flight
  loadA(0);                 // A0 x8
  stageB(0, 0);             // B0 x2
  WAIT_VM(2); SCHED_FENCE();   // A0 landed (B0 may fly)
  writeA(0);
  loadA(BK);                // A1 x8
  stageB(1, BK);            // B1 x2
  WAIT_LGKM0(); SCHED_FENCE(); // A0 ds_writes drained (barrier W below makes collective)

  for (int ti = 0; ti < NT; ++ti) {
    if (ti < NT - 1) { WAIT_VM(10); } else { WAIT_VM(0); }  // B(ti) landed
    SCHED_FENCE();
    __builtin_amdgcn_s_barrier();                           // W: tile ti ready

    const int buf = ti & 1;
    const char* as = (const char*)&As[buf][0];
    const char* bs = (const char*)&Bs[buf][0];
#pragma unroll
    for (int ks = 0; ks < 2; ++ks) {
      short8 a[4], b[2];
      const int cc = ks * 4 + quad;
#pragma unroll
      for (int i = 0; i < 4; ++i) {
        const int ar = wm + i * 16 + r16;
        a[i] = *reinterpret_cast<const short8*>(as + (ar * 8 + (cc ^ (ar & 7))) * 16);
      }
#pragma unroll
      for (int j = 0; j < 2; ++j) {
        const int br = wn + j * 16 + r16;
        b[j] = *reinterpret_cast<const short8*>(bs + (br * 8 + (cc ^ (br & 7))) * 16);
      }
#pragma unroll
      for (int i = 0; i < 4; ++i)
#pragma unroll
        for (int j = 0; j < 2; ++j)
          acc[i][j] = __builtin_amdgcn_mfma_f32_16x16x32_bf16(a[i], b[j], acc[i][j], 0, 0, 0);
    }

    if (ti + 1 < NT) {
      WAIT_VM(2); SCHED_FENCE();   // A(ti+1) regs landed; B(ti+1) stays in flight
      writeA(buf ^ 1);             // safe: all waves passed R(ti-1) (via W(ti))
      WAIT_LGKM0(); SCHED_FENCE(); // writes drained before R
    }
    __builtin_amdgcn_s_barrier();  // R: readers of buf done; A-writes collective
    if (ti + 2 < NT) { loadA((ti + 2) * BK); stageB(buf, (ti + 2) * BK); }
  }

#pragma unroll
  for (int i = 0; i < 4; ++i)
#pragma unroll
    for (int j = 0; j < 2; ++j)
#pragma unroll
      for (int r = 0; r < 4; ++r) {
        const int row = tm0 + wm + i * 16 + quad * 4 + r;
        const int col = tn0 + wn + j * 16 + r16;
        C[(size_t)row * N + col] = __float2bfloat16(acc[i][j][r]);
      }
}

// ---------------- GEMM2: Y[M,4096] = H[M,512] @ W2[4096,512]^T + bias ------
// Unchanged from r4: counted-vmcnt pipeline, 8 loads/thread/tile -> vmcnt(8),
// 64 KB LDS dbuf, 2 blocks/CU.
__global__ __launch_bounds__(256, 2)
void gemm2_kernel(const __hip_bfloat16* __restrict__ A,
                  const __hip_bfloat16* __restrict__ B,
                  const float* __restrict__ bias,
                  float* __restrict__ C) {
  constexpr int K = S2;        // 512
  constexpr int N = OUT_DIM;   // 4096
  constexpr int BM = 128, BN = 128, BK = 64;
  constexpr int NT = K / BK;   // 8 tiles

  __shared__ __hip_bfloat16 As[2][BM * BK];   // 2 x 16 KB
  __shared__ __hip_bfloat16 Bs[2][BN * BK];   // 2 x 16 KB

  const int t = threadIdx.x;
  const int wave = t >> 6;
  const int lane = t & 63;
  const int r16 = lane & 15;
  const int quad = lane >> 4;

  // XCD swizzle: 2048 blocks; XCD c handles M-tiles [c*8,c*8+8) x all 32 N-tiles.
  const int f = blockIdx.x;
  const int c = f & 7;
  const int l = f >> 3;              // [0,256)
  const int tm0 = (c * 8 + (l >> 5)) * BM;
  const int tn0 = (l & 31) * BN;

  const int wm = (wave & 1) * 64;
  const int wn = (wave >> 1) * 64;

  floatx4 acc[4][4] = {};

  auto stage = [&](int buf, int k0) {   // 8 vmem ops/thread/tile
#pragma unroll
    for (int i = 0; i < 4; ++i) {
      const int p = t + i * 256;
      const int row = p >> 3;
      const int ql = (p & 7) ^ (row & 7);
      const __hip_bfloat16* gp = A + (size_t)(tm0 + row) * K + k0 + ql * 8;
      __builtin_amdgcn_global_load_lds(AS_GLOBAL(gp), AS_LDS((char*)&As[buf][0] + p * 16), 16, 0, 0);
    }
#pragma unroll
    for (int i = 0; i < 4; ++i) {
      const int p = t + i * 256;
      const int row = p >> 3;
      const int ql = (p & 7) ^ (row & 7);
      const __hip_bfloat16* gp = B + (size_t)(tn0 + row) * K + k0 + ql * 8;
      __builtin_amdgcn_global_load_lds(AS_GLOBAL(gp), AS_LDS((char*)&Bs[buf][0] + p * 16), 16, 0, 0);
    }
  };

  stage(0, 0);
  stage(1, BK);        // 16 loads in flight

  for (int ti = 0; ti < NT; ++ti) {
    if (ti < NT - 1) { WAIT_VM(8); } else { WAIT_VM(0); }
    SCHED_FENCE();
    __builtin_amdgcn_s_barrier();

    const int buf = ti & 1;
    const char* as = (const char*)&As[buf][0];
    const char* bs = (const char*)&Bs[buf][0];
#pragma unroll
    for (int ks = 0; ks < 2; ++ks) {
      short8 a[4], b[4];
      const int cc = ks * 4 + quad;
#pragma unroll
      for (int i = 0; i < 4; ++i) {
        const int ar = wm + i * 16 + r16;
        a[i] = *reinterpret_cast<const short8*>(as + (ar * 8 + (cc ^ (ar & 7))) * 16);
      }
#pragma unroll
      for (int j = 0; j < 4; ++j) {
        const int br = wn + j * 16 + r16;
        b[j] = *reinterpret_cast<const short8*>(bs + (br * 8 + (cc ^ (br & 7))) * 16);
      }
#pragma unroll
      for (int i = 0; i < 4; ++i)
#pragma unroll
        for (int j = 0; j < 4; ++j)
          acc[i][j] = __builtin_amdgcn_mfma_f32_16x16x32_bf16(a[i], b[j], acc[i][j], 0, 0, 0);
    }

    __builtin_amdgcn_s_barrier();
    if (ti + 2 < NT) stage(buf, (ti + 2) * BK);
  }

  // epilogue: bias + fp32 store
  float bi[4];
#pragma unroll
  for (int j = 0; j < 4; ++j) bi[j] = bias[tn0 + wn + j * 16 + r16];

#pragma unroll
  for (int i = 0; i < 4; ++i)
#pragma unroll
    for (int j = 0; j < 4; ++j)
#pragma unroll
      for (int r = 0; r < 4; ++r) {
        const int row = tm0 + wm + i * 16 + quad * 4 + r;
        const int col = tn0 + wn + j * 16 + r16;
        C[(size_t)row * N + col] = acc[i][j][r] + bi[j];
      }
}

// ---------------- launch ----------------
extern "C" void kernel_launch(void* const* d_in, const int* in_sizes, int n_in,
                              void* d_out, int out_size, void* d_ws, size_t ws_size,
                              hipStream_t stream) {
  const float* x    = (const float*)d_in[0];
  const float* V    = (const float*)d_in[1];
  const float* U    = (const float*)d_in[2];
  const float* v1   = (const float*)d_in[3];
  const float* v2   = (const float*)d_in[4];
  const float* u1   = (const float*)d_in[5];
  const float* u2   = (const float*)d_in[6];
  const float* V_R  = (const float*)d_in[7];
  const float* U_R  = (const float*)d_in[8];
  const float* v1_R = (const float*)d_in[9];
  const float* v2_R = (const float*)d_in[10];
  const float* u1_R = (const float*)d_in[11];
  const float* u2_R = (const float*)d_in[12];
  const float* bias = (const float*)d_in[13];
  float* out = (float*)d_out;

  const int M = in_sizes[0] / IN_DIM;   // 8192

  char* ws = (char*)d_ws;
  __hip_bfloat16* W1 = (__hip_bfloat16*)ws;                                   // 4 MB
  __hip_bfloat16* W2 = (__hip_bfloat16*)(ws + (size_t)4 * 1024 * 1024);       // 4 MB
  __hip_bfloat16* H  = (__hip_bfloat16*)(ws + (size_t)8 * 1024 * 1024);       // M*512*2 = 8 MB

  // prep: W1 + W2 only (no x-conversion pass)
  prep_kernel<<<4096, 256, 0, stream>>>(
      V, v2, V_R, v2_R, U, u1, v1, u2, U_R, u1_R, v1_R, u2_R, W1, W2);

  // GEMM1: (M/128) x (512/64) = 64 x 8 = 512 blocks, reads fp32 x directly
  gemm1_kernel<<<(M / 128) * (S2 / 64), 256, 0, stream>>>(x, W1, H);

  // GEMM2: (M/128) x (4096/128) = 64 x 32 = 2048 blocks
  gemm2_kernel<<<(M / 128) * (OUT_DIM / 128), 256, 0, stream>>>(H, W2, bias, out);
}